// Round 3
// baseline (570.193 us; speedup 1.0000x reference)
//
#include <hip/hip_runtime.h>

// ---------------- problem constants ----------------
#define B_DIM   4096
#define INF     512      // IN_DIM
#define UNITS_  1024
#define SUBD    512
#define NSUB_   3
#define NBAS    8        // GRID_SIZE + SPLINE_ORDER
#define G3K     (SUBD * NBAS)   // 4096 spline reduction dim

typedef __attribute__((ext_vector_type(8))) short bf16x8_t;   // 8 bf16 (4 VGPR)
typedef __attribute__((ext_vector_type(4))) float f32x4_t;    // MFMA acc
typedef unsigned short u16;

__device__ __forceinline__ u16 f2bf(float f) {
    union { float f; unsigned int u; } v; v.f = f;
    unsigned int r = v.u + 0x7fffu + ((v.u >> 16) & 1u);   // RNE
    return (u16)(r >> 16);
}
__device__ __forceinline__ float bf2f(u16 h) {
    union { unsigned int u; float f; } v; v.u = ((unsigned int)h) << 16;
    return v.f;
}
__device__ __forceinline__ float sigm(float x) { return 1.0f / (1.0f + __expf(-x)); }
__device__ __forceinline__ float tanh_(float x) {
    float e = __expf(2.0f * x);
    return 1.0f - 2.0f / (e + 1.0f);
}

// async global->LDS, 16B per lane. LDS dest must be wave-uniform base (+lane*16 implicit).
__device__ __forceinline__ void gload_lds16(const void* g, void* l) {
    __builtin_amdgcn_global_load_lds(
        (const __attribute__((address_space(1))) unsigned int*)g,
        (__attribute__((address_space(3))) unsigned int*)l, 16, 0, 0);
}

// ---------------- elementwise converts ----------------
__global__ void k_f32_to_bf16(const float* __restrict__ in, u16* __restrict__ out, int n4) {
    int i = blockIdx.x * blockDim.x + threadIdx.x;
    if (i >= n4) return;
    float4 v = ((const float4*)in)[i];
    ushort4 r; r.x = f2bf(v.x); r.y = f2bf(v.y); r.z = f2bf(v.z); r.w = f2bf(v.w);
    ((ushort4*)out)[i] = r;
}

// scaled spline weight: out = bf16(sw * scaler[idx>>3])
__global__ void k_ssw(const float* __restrict__ sw, const float* __restrict__ sc,
                      u16* __restrict__ out, int n4) {
    int i = blockIdx.x * blockDim.x + threadIdx.x;
    if (i >= n4) return;
    float4 v = ((const float4*)sw)[i];
    float s = sc[i >> 1];                  // (i*4)>>3 == i>>1 (4-vec never crosses the 8-group)
    ushort4 r; r.x = f2bf(v.x * s); r.y = f2bf(v.y * s); r.z = f2bf(v.z * s); r.w = f2bf(v.w * s);
    ((ushort4*)out)[i] = r;
}

// transpose + convert: out[C][R] bf16 = in[R][C] f32.  block (32,8), grid (C/32, R/32, batch)
__global__ void k_tconv(const float* __restrict__ in, u16* __restrict__ out,
                        int R, int C, size_t inStride, size_t outStride) {
    in  += (size_t)blockIdx.z * inStride;
    out += (size_t)blockIdx.z * outStride;
    __shared__ float tile[32][33];
    int c0 = blockIdx.x * 32, r0 = blockIdx.y * 32;
    int tx = threadIdx.x, ty = threadIdx.y;
#pragma unroll
    for (int j = 0; j < 4; ++j)
        tile[ty + j * 8][tx] = in[(size_t)(r0 + ty + j * 8) * C + c0 + tx];
    __syncthreads();
#pragma unroll
    for (int j = 0; j < 4; ++j)
        out[(size_t)(c0 + ty + j * 8) * R + r0 + tx] = f2bf(tile[tx][ty + j * 8]);
}

// c_new = f*c0 + i*tanh(c_gate), gates already sigmoided (bf16 in gbuf, cols [i|f|c])
__global__ void k_cnew(const u16* __restrict__ gbuf, const float* __restrict__ c0,
                       float* __restrict__ c_out, int n4) {
    int i = blockIdx.x * blockDim.x + threadIdx.x;
    if (i >= n4) return;
    int u4 = i * 4;
    int b = u4 >> 10, u = u4 & 1023;
    const u16* gr = gbuf + (size_t)b * 3072 + u;
    ushort4 gi = *(const ushort4*)gr;
    ushort4 gf = *(const ushort4*)(gr + 1024);
    ushort4 gc = *(const ushort4*)(gr + 2048);
    float4 c0v = ((const float4*)c0)[i];
    float4 r;
    r.x = bf2f(gf.x) * c0v.x + bf2f(gi.x) * tanh_(bf2f(gc.x));
    r.y = bf2f(gf.y) * c0v.y + bf2f(gi.y) * tanh_(bf2f(gc.y));
    r.z = bf2f(gf.z) * c0v.z + bf2f(gi.z) * tanh_(bf2f(gc.z));
    r.w = bf2f(gf.w) * c0v.w + bf2f(gi.w) * tanh_(bf2f(gc.w));
    ((float4*)c_out)[i] = r;
}

// per agg element: silu (bf16) and the 8 cubic B-spline bases (bf16x8, one 16B store)
// knots t_j = (j-3)*1.2 - 3, j = 0..11  (exactly the reference make_grid formula)
__global__ void k_bases(const float* __restrict__ agg, u16* __restrict__ bases,
                        u16* __restrict__ silu, int n) {
    for (int i = blockIdx.x * blockDim.x + threadIdx.x; i < n; i += gridDim.x * blockDim.x) {
        float x = agg[i];
        silu[i] = f2bf(x * sigm(x));
        float b[11];
#pragma unroll
        for (int j = 0; j < 11; ++j) {
            float tj  = 1.2f * (float)(j - 3) - 3.0f;
            float tj1 = 1.2f * (float)(j - 2) - 3.0f;
            b[j] = (x >= tj && x < tj1) ? 1.0f : 0.0f;
        }
#pragma unroll
        for (int k = 1; k <= 3; ++k) {
            float inv = 1.0f / (1.2f * (float)k);
#pragma unroll
            for (int j = 0; j < 11; ++j) {
                if (j > 10 - k) break;
                float tj   = 1.2f * (float)(j - 3) - 3.0f;
                float tjk1 = 1.2f * (float)(j + k - 2) - 3.0f;   // t_{j+k+1}
                b[j] = (x - tj) * inv * b[j] + (tjk1 - x) * inv * b[j + 1];
            }
        }
        bf16x8_t v;
#pragma unroll
        for (int j = 0; j < 8; ++j) v[j] = (short)f2bf(b[j]);
        *(bf16x8_t*)(bases + (size_t)i * 8) = v;
    }
}

// ---------------- MFMA GEMM core ----------------
// 128x128 tile, 512 threads = 2 groups x 4 waves. In-block split-K: group g computes
// K-range [g*nkt/2, (g+1)*nkt/2) into its own 32KB LDS pair; partial accs combined
// through LDS (f32 128x128 = exactly the 64KB staging region, reused) at the end.
// Doubles waves/CU vs 4-wave blocks with zero extra HBM traffic.
struct Seg { const u16* A; const u16* B; int ldA; int ldB; int nkt; };

template<int NS>
__device__ __forceinline__ void gemm_core8(const Seg segs[NS], int rowBase, int colBase,
                                           u16* smem, f32x4_t acc[4][4]) {
    const int t = threadIdx.x;
    const int lane = t & 63, wave = t >> 6;
    const int grp = wave >> 2, w4 = wave & 3;
    const int wR = (w4 >> 1) * 64, wC = (w4 & 1) * 64;
    const int l15 = lane & 15, lk = (lane >> 4) * 8;
    const int sr = lane >> 3, scol = (lane & 7) * 8;
    u16* lA = smem + grp * 16384;   // 16KB A tile per group
    u16* lB = lA + 8192;            // 16KB B tile per group
#pragma unroll
    for (int s = 0; s < NS; ++s) {
        const u16* Ag = segs[s].A + (size_t)rowBase * segs[s].ldA;
        const u16* Bg = segs[s].B + (size_t)colBase * segs[s].ldB;
        const int ldA = segs[s].ldA, ldB = segs[s].ldB;
        const int khalf = segs[s].nkt >> 1;
        const int k0 = grp * khalf;
        for (int kt = 0; kt < khalf; ++kt) {
            __syncthreads();   // previous compute done before LDS overwrite
#pragma unroll
            for (int i = 0; i < 4; ++i) {
                int ci = w4 * 4 + i;     // chunk: 8 rows = 1024 B (64 lanes x 16 B)
                int r = ci * 8 + sr;
                gload_lds16(Ag + (size_t)r * ldA + (k0 + kt) * 64 + scol, lA + ci * 512);
                gload_lds16(Bg + (size_t)r * ldB + (k0 + kt) * 64 + scol, lB + ci * 512);
            }
            __syncthreads();   // barrier drains vmcnt -> LDS tiles complete
#pragma unroll
            for (int kk = 0; kk < 2; ++kk) {
                bf16x8_t a[4], b[4];
#pragma unroll
                for (int m = 0; m < 4; ++m)
                    a[m] = *(const bf16x8_t*)(lA + (wR + m * 16 + l15) * 64 + kk * 32 + lk);
#pragma unroll
                for (int n = 0; n < 4; ++n)
                    b[n] = *(const bf16x8_t*)(lB + (wC + n * 16 + l15) * 64 + kk * 32 + lk);
#pragma unroll
                for (int m = 0; m < 4; ++m)
#pragma unroll
                    for (int n = 0; n < 4; ++n)
                        acc[m][n] = __builtin_amdgcn_mfma_f32_16x16x32_bf16(a[m], b[n], acc[m][n], 0, 0, 0);
            }
        }
    }
    // combine: group1 partial -> LDS -> group0 acc (group0 then owns the full sum)
    __syncthreads();
    float* red = (float*)smem;
    const int r4 = (lane >> 4) * 4;
    if (grp == 1) {
#pragma unroll
        for (int m = 0; m < 4; ++m)
#pragma unroll
            for (int n = 0; n < 4; ++n)
#pragma unroll
                for (int j = 0; j < 4; ++j)
                    red[(wR + m * 16 + r4 + j) * 128 + wC + n * 16 + l15] = acc[m][n][j];
    }
    __syncthreads();
    if (grp == 0) {
#pragma unroll
        for (int m = 0; m < 4; ++m)
#pragma unroll
            for (int n = 0; n < 4; ++n)
#pragma unroll
                for (int j = 0; j < 4; ++j)
                    acc[m][n][j] += red[(wR + m * 16 + r4 + j) * 128 + wC + n * 16 + l15];
    }
}

// block-id decode; optional bijective XCD swizzle (m204): contiguous wg chunks per XCD,
// col fastest -> col-blocks sharing an A-panel co-resident on one XCD's L2.
template<int NCOL, int NROW, int NWG, bool SWZ>
__device__ __forceinline__ void decode_wg(int o, int& col, int& row, int& kz) {
    int wg = o;
    if (SWZ) {
        constexpr int q = NWG / 8, r = NWG % 8;
        int xcd = o & 7, idx = o >> 3;
        wg = (xcd < r ? xcd * (q + 1) : r * (q + 1) + (xcd - r) * q) + idx;
    }
    col = wg % NCOL; int tmp = wg / NCOL; row = tmp % NROW; kz = tmp / NROW;
}

#define GEMM_PRE8(NCOL, NROW, NWG, SWZ)                                    \
    __shared__ u16 smem[32768];  /* 64 KB */                               \
    int col_, row_, kz_;                                                   \
    decode_wg<NCOL, NROW, NWG, SWZ>(blockIdx.x, col_, row_, kz_);          \
    int rowBase = row_ * 128, colBase = col_ * 128;                        \
    f32x4_t acc[4][4];                                                     \
    _Pragma("unroll") for (int m = 0; m < 4; ++m)                          \
        _Pragma("unroll") for (int n = 0; n < 4; ++n)                      \
            acc[m][n] = (f32x4_t){0.f, 0.f, 0.f, 0.f};

#define EPI_IDX8()                                                         \
    const int lane = threadIdx.x & 63, wave = (threadIdx.x >> 6) & 3;      \
    const int wR = (wave >> 1) * 64, wC = (wave & 1) * 64;                 \
    const int l15 = lane & 15, r4 = (lane >> 4) * 4;

// z-GEMM: g = sigmoid(x@Wk + h0@Wr + bias) -> gbuf bf16 (4096 x 3072)
__global__ __launch_bounds__(512) void k_gemm1(const u16* xb, const u16* h0b,
                                               const u16* kT, const u16* rkT,
                                               const float* __restrict__ bias,
                                               u16* __restrict__ gbuf) {
    GEMM_PRE8(24, 32, 768, false);
    Seg segs[2] = { { xb, kT, INF, INF, INF / 64 },
                    { h0b, rkT, UNITS_, UNITS_, UNITS_ / 64 } };
    gemm_core8<2>(segs, rowBase, colBase, smem, acc);
    if (threadIdx.x < 256) {
        EPI_IDX8();
#pragma unroll
        for (int m = 0; m < 4; ++m)
#pragma unroll
            for (int n = 0; n < 4; ++n)
#pragma unroll
                for (int j = 0; j < 4; ++j) {
                    int row = rowBase + wR + m * 16 + r4 + j;
                    int col = colBase + wC + n * 16 + l15;
                    gbuf[(size_t)row * 3072 + col] = f2bf(sigm(acc[m][n][j] + bias[col]));
                }
    }
}

// agg GEMM: agg[k] = x@ski[k] + ss[k]@sks[k]  -> f32 (3 x 4096 x 512)
__global__ __launch_bounds__(512) void k_gemm2(const u16* xb, const u16* ssb,
                                               const u16* skiT, const u16* sksT,
                                               float* __restrict__ agg) {
    GEMM_PRE8(4, 32, 384, false);
    int k = kz_;
    Seg segs[2] = { { xb, skiT + (size_t)k * SUBD * INF, INF, INF, INF / 64 },
                    { ssb + (size_t)k * B_DIM * SUBD, sksT + (size_t)k * SUBD * SUBD, SUBD, SUBD, SUBD / 64 } };
    gemm_core8<2>(segs, rowBase, colBase, smem, acc);
    if (threadIdx.x < 256) {
        EPI_IDX8();
#pragma unroll
        for (int m = 0; m < 4; ++m)
#pragma unroll
            for (int n = 0; n < 4; ++n)
#pragma unroll
                for (int j = 0; j < 4; ++j) {
                    int row = rowBase + wR + m * 16 + r4 + j;
                    int col = colBase + wC + n * 16 + l15;
                    agg[((size_t)k * B_DIM + row) * SUBD + col] = acc[m][n][j];
                }
    }
}

// sub_out GEMM: silu(agg)@bw^T + bases@ssw^T; epilogue -> new_sub_states (f32 out) + subflat bf16
__global__ __launch_bounds__(512) void k_gemm3(const u16* silu, const u16* bases,
                                               const u16* bwb, const u16* sswb,
                                               const float* __restrict__ srk,
                                               const float* __restrict__ ss,
                                               float* __restrict__ nss_out,
                                               u16* __restrict__ subfl) {
    GEMM_PRE8(4, 32, 384, true);   // XCD swizzle: 4 col-blocks of a row-panel share one XCD L2
    int k = kz_;
    Seg segs[2] = { { silu + (size_t)k * B_DIM * SUBD, bwb + (size_t)k * SUBD * SUBD, SUBD, SUBD, SUBD / 64 },
                    { bases + (size_t)k * B_DIM * G3K, sswb + (size_t)k * SUBD * G3K, G3K, G3K, G3K / 64 } };
    gemm_core8<2>(segs, rowBase, colBase, smem, acc);
    if (threadIdx.x < 256) {
        EPI_IDX8();
#pragma unroll
        for (int m = 0; m < 4; ++m)
#pragma unroll
            for (int n = 0; n < 4; ++n)
#pragma unroll
                for (int j = 0; j < 4; ++j) {
                    int row = rowBase + wR + m * 16 + r4 + j;
                    int col = colBase + wC + n * 16 + l15;
                    float so = acc[m][n][j];
                    float rh = srk[k * 1024 + col];
                    float rx = srk[k * 1024 + 512 + col];
                    size_t o = ((size_t)k * B_DIM + row) * SUBD + col;
                    nss_out[o] = rh * so + rx * ss[o];
                    subfl[(size_t)row * 1536 + k * SUBD + col] = f2bf(so);
                }
    }
}

// output GEMM: h = sigmoid(subflat@aw + ab) * tanh(c_new)
__global__ __launch_bounds__(512) void k_gemm4(const u16* subfl, const u16* awT,
                                               const float* __restrict__ abias,
                                               const float* __restrict__ c_new,
                                               float* __restrict__ h_out) {
    GEMM_PRE8(8, 32, 256, false);
    Seg segs[1] = { { subfl, awT, 1536, 1536, 1536 / 64 } };
    gemm_core8<1>(segs, rowBase, colBase, smem, acc);
    if (threadIdx.x < 256) {
        EPI_IDX8();
#pragma unroll
        for (int m = 0; m < 4; ++m)
#pragma unroll
            for (int n = 0; n < 4; ++n)
#pragma unroll
                for (int j = 0; j < 4; ++j) {
                    int row = rowBase + wR + m * 16 + r4 + j;
                    int col = colBase + wC + n * 16 + l15;
                    float ov = sigm(acc[m][n][j] + abias[col]);
                    h_out[(size_t)row * 1024 + col] = ov * tanh_(c_new[(size_t)row * 1024 + col]);
                }
    }
}

// ---------------- launch ----------------
extern "C" void kernel_launch(void* const* d_in, const int* in_sizes, int n_in,
                              void* d_out, int out_size, void* d_ws, size_t ws_size,
                              hipStream_t stream) {
    const float* x    = (const float*)d_in[0];
    const float* h0   = (const float*)d_in[1];
    const float* c0   = (const float*)d_in[2];
    const float* ss   = (const float*)d_in[3];
    const float* Wk   = (const float*)d_in[4];
    const float* Wr   = (const float*)d_in[5];
    const float* bias = (const float*)d_in[6];
    const float* ski  = (const float*)d_in[7];
    const float* sks  = (const float*)d_in[8];
    const float* srk  = (const float*)d_in[9];
    const float* bw   = (const float*)d_in[10];
    const float* sw   = (const float*)d_in[11];
    const float* sc   = (const float*)d_in[12];
    const float* aw   = (const float*)d_in[13];
    const float* ab   = (const float*)d_in[14];

    float* out_h   = (float*)d_out;
    float* out_c   = out_h + (size_t)B_DIM * UNITS_;
    float* out_nss = out_c + (size_t)B_DIM * UNITS_;

    char* w = (char*)d_ws;
    auto take = [&](size_t bytes) -> char* {
        char* p = w; w += (bytes + 255) & ~(size_t)255; return p;
    };
    u16*   xb    = (u16*)take((size_t)B_DIM * INF * 2);
    u16*   h0b   = (u16*)take((size_t)B_DIM * UNITS_ * 2);
    u16*   ssb   = (u16*)take((size_t)NSUB_ * B_DIM * SUBD * 2);
    u16*   kT    = (u16*)take((size_t)3072 * INF * 2);
    u16*   rkT   = (u16*)take((size_t)3072 * UNITS_ * 2);
    u16*   skiT  = (u16*)take((size_t)NSUB_ * SUBD * INF * 2);
    u16*   sksT  = (u16*)take((size_t)NSUB_ * SUBD * SUBD * 2);
    u16*   bwb   = (u16*)take((size_t)NSUB_ * SUBD * SUBD * 2);
    u16*   sswb  = (u16*)take((size_t)NSUB_ * SUBD * G3K * 2);
    u16*   awT   = (u16*)take((size_t)UNITS_ * 1536 * 2);
    float* agg   = (float*)take((size_t)NSUB_ * B_DIM * SUBD * 4);
    u16*   siluB = (u16*)take((size_t)NSUB_ * B_DIM * SUBD * 2);
    u16*   subfl = (u16*)take((size_t)B_DIM * 1536 * 2);
    u16*   basesB= (u16*)take((size_t)NSUB_ * B_DIM * G3K * 2);
    u16*   gbuf  = basesB;   // alias: gbuf (25 MB) is dead before basesB is written

    dim3 tb(256);
    // converts
    k_f32_to_bf16<<<(B_DIM * INF / 4 + 255) / 256, tb, 0, stream>>>(x, xb, B_DIM * INF / 4);
    k_f32_to_bf16<<<(B_DIM * UNITS_ / 4 + 255) / 256, tb, 0, stream>>>(h0, h0b, B_DIM * UNITS_ / 4);
    k_f32_to_bf16<<<(NSUB_ * B_DIM * SUBD / 4 + 255) / 256, tb, 0, stream>>>(ss, ssb, NSUB_ * B_DIM * SUBD / 4);
    k_f32_to_bf16<<<(NSUB_ * SUBD * SUBD / 4 + 255) / 256, tb, 0, stream>>>(bw, bwb, NSUB_ * SUBD * SUBD / 4);
    k_ssw<<<(NSUB_ * SUBD * G3K / 4 + 255) / 256, tb, 0, stream>>>(sw, sc, sswb, NSUB_ * SUBD * G3K / 4);
    dim3 tt(32, 8);
    k_tconv<<<dim3(3072 / 32, INF / 32, 1), tt, 0, stream>>>(Wk, kT, INF, 3072, 0, 0);
    k_tconv<<<dim3(3072 / 32, UNITS_ / 32, 1), tt, 0, stream>>>(Wr, rkT, UNITS_, 3072, 0, 0);
    k_tconv<<<dim3(SUBD / 32, INF / 32, NSUB_), tt, 0, stream>>>(ski, skiT, INF, SUBD,
                                                                 (size_t)INF * SUBD, (size_t)SUBD * INF);
    k_tconv<<<dim3(SUBD / 32, SUBD / 32, NSUB_), tt, 0, stream>>>(sks, sksT, SUBD, SUBD,
                                                                  (size_t)SUBD * SUBD, (size_t)SUBD * SUBD);
    k_tconv<<<dim3(UNITS_ / 32, 1536 / 32, 1), tt, 0, stream>>>(aw, awT, 1536, UNITS_, 0, 0);

    // gate GEMM + c_new
    k_gemm1<<<768, 512, 0, stream>>>(xb, h0b, kT, rkT, bias, gbuf);
    k_gemm2<<<384, 512, 0, stream>>>(xb, ssb, skiT, sksT, agg);
    k_cnew<<<(B_DIM * UNITS_ / 4 + 255) / 256, tb, 0, stream>>>(gbuf, c0, out_c, B_DIM * UNITS_ / 4);

    // spline bases + silu (gbuf region now dead -> basesB reuse OK)
    k_bases<<<4096, tb, 0, stream>>>(agg, basesB, siluB, NSUB_ * B_DIM * SUBD);

    // sub_out GEMM (base K=512 + spline K=4096), epilogue writes new_sub_states + subflat
    k_gemm3<<<384, 512, 0, stream>>>(siluB, basesB, bwb, sswb, srk, ss, out_nss, subfl);
    // aggregation GEMM + h_new
    k_gemm4<<<256, 512, 0, stream>>>(subfl, awT, ab, out_c, out_h);
}

// Round 4
// 500.938 us; speedup vs baseline: 1.1382x; 1.1382x over previous
//
#include <hip/hip_runtime.h>

// ---------------- problem constants ----------------
#define B_DIM   4096
#define INF     512      // IN_DIM
#define UNITS_  1024
#define SUBD    512
#define NSUB_   3
#define NBAS    8        // GRID_SIZE + SPLINE_ORDER
#define G3K     (SUBD * NBAS)   // 4096 spline reduction dim

typedef __attribute__((ext_vector_type(8))) short bf16x8_t;   // 8 bf16 (4 VGPR)
typedef __attribute__((ext_vector_type(4))) float f32x4_t;    // MFMA acc
typedef unsigned short u16;

__device__ __forceinline__ u16 f2bf(float f) {
    union { float f; unsigned int u; } v; v.f = f;
    unsigned int r = v.u + 0x7fffu + ((v.u >> 16) & 1u);   // RNE
    return (u16)(r >> 16);
}
__device__ __forceinline__ float bf2f(u16 h) {
    union { unsigned int u; float f; } v; v.u = ((unsigned int)h) << 16;
    return v.f;
}
__device__ __forceinline__ float sigm(float x) { return 1.0f / (1.0f + __expf(-x)); }
__device__ __forceinline__ float tanh_(float x) {
    float e = __expf(2.0f * x);
    return 1.0f - 2.0f / (e + 1.0f);
}

// async global->LDS, 16B per lane. LDS dest must be wave-uniform base (+lane*16 implicit).
__device__ __forceinline__ void gload_lds16(const void* g, void* l) {
    __builtin_amdgcn_global_load_lds(
        (const __attribute__((address_space(1))) unsigned int*)g,
        (__attribute__((address_space(3))) unsigned int*)l, 16, 0, 0);
}

// ---------------- elementwise converts ----------------
__global__ void k_f32_to_bf16(const float* __restrict__ in, u16* __restrict__ out, int n4) {
    int i = blockIdx.x * blockDim.x + threadIdx.x;
    if (i >= n4) return;
    float4 v = ((const float4*)in)[i];
    ushort4 r; r.x = f2bf(v.x); r.y = f2bf(v.y); r.z = f2bf(v.z); r.w = f2bf(v.w);
    ((ushort4*)out)[i] = r;
}

// scaled spline weight: out = bf16(sw * scaler[idx>>3])
__global__ void k_ssw(const float* __restrict__ sw, const float* __restrict__ sc,
                      u16* __restrict__ out, int n4) {
    int i = blockIdx.x * blockDim.x + threadIdx.x;
    if (i >= n4) return;
    float4 v = ((const float4*)sw)[i];
    float s = sc[i >> 1];                  // (i*4)>>3 == i>>1 (4-vec never crosses the 8-group)
    ushort4 r; r.x = f2bf(v.x * s); r.y = f2bf(v.y * s); r.z = f2bf(v.z * s); r.w = f2bf(v.w * s);
    ((ushort4*)out)[i] = r;
}

// transpose + convert: out[C][R] bf16 = in[R][C] f32.  block (32,8), grid (C/32, R/32, batch)
__global__ void k_tconv(const float* __restrict__ in, u16* __restrict__ out,
                        int R, int C, size_t inStride, size_t outStride) {
    in  += (size_t)blockIdx.z * inStride;
    out += (size_t)blockIdx.z * outStride;
    __shared__ float tile[32][33];
    int c0 = blockIdx.x * 32, r0 = blockIdx.y * 32;
    int tx = threadIdx.x, ty = threadIdx.y;
#pragma unroll
    for (int j = 0; j < 4; ++j)
        tile[ty + j * 8][tx] = in[(size_t)(r0 + ty + j * 8) * C + c0 + tx];
    __syncthreads();
#pragma unroll
    for (int j = 0; j < 4; ++j)
        out[(size_t)(c0 + ty + j * 8) * R + r0 + tx] = f2bf(tile[tx][ty + j * 8]);
}

// c_new = f*c0 + i*tanh(c_gate), gates already sigmoided (bf16 in gbuf, cols [i|f|c])
__global__ void k_cnew(const u16* __restrict__ gbuf, const float* __restrict__ c0,
                       float* __restrict__ c_out, int n4) {
    int i = blockIdx.x * blockDim.x + threadIdx.x;
    if (i >= n4) return;
    int u4 = i * 4;
    int b = u4 >> 10, u = u4 & 1023;
    const u16* gr = gbuf + (size_t)b * 3072 + u;
    ushort4 gi = *(const ushort4*)gr;
    ushort4 gf = *(const ushort4*)(gr + 1024);
    ushort4 gc = *(const ushort4*)(gr + 2048);
    float4 c0v = ((const float4*)c0)[i];
    float4 r;
    r.x = bf2f(gf.x) * c0v.x + bf2f(gi.x) * tanh_(bf2f(gc.x));
    r.y = bf2f(gf.y) * c0v.y + bf2f(gi.y) * tanh_(bf2f(gc.y));
    r.z = bf2f(gf.z) * c0v.z + bf2f(gi.z) * tanh_(bf2f(gc.z));
    r.w = bf2f(gf.w) * c0v.w + bf2f(gi.w) * tanh_(bf2f(gc.w));
    ((float4*)c_out)[i] = r;
}

// per agg element: silu (bf16) and the 8 cubic B-spline bases (bf16x8, one 16B store)
// knots t_j = (j-3)*1.2 - 3, j = 0..11  (exactly the reference make_grid formula)
__global__ void k_bases(const float* __restrict__ agg, u16* __restrict__ bases,
                        u16* __restrict__ silu, int n) {
    for (int i = blockIdx.x * blockDim.x + threadIdx.x; i < n; i += gridDim.x * blockDim.x) {
        float x = agg[i];
        silu[i] = f2bf(x * sigm(x));
        float b[11];
#pragma unroll
        for (int j = 0; j < 11; ++j) {
            float tj  = 1.2f * (float)(j - 3) - 3.0f;
            float tj1 = 1.2f * (float)(j - 2) - 3.0f;
            b[j] = (x >= tj && x < tj1) ? 1.0f : 0.0f;
        }
#pragma unroll
        for (int k = 1; k <= 3; ++k) {
            float inv = 1.0f / (1.2f * (float)k);
#pragma unroll
            for (int j = 0; j < 11; ++j) {
                if (j > 10 - k) break;
                float tj   = 1.2f * (float)(j - 3) - 3.0f;
                float tjk1 = 1.2f * (float)(j + k - 2) - 3.0f;   // t_{j+k+1}
                b[j] = (x - tj) * inv * b[j] + (tjk1 - x) * inv * b[j + 1];
            }
        }
        bf16x8_t v;
#pragma unroll
        for (int j = 0; j < 8; ++j) v[j] = (short)f2bf(b[j]);
        *(bf16x8_t*)(bases + (size_t)i * 8) = v;
    }
}

// ---------------- MFMA GEMM core ----------------
// 128xBN tile (BN = 64 or 128), BK=64, 4 waves / 256 threads, B^T operands.
// m97-structure: global_load_lds width=16, linear LDS, 2 barriers/K-step.
// BN=64 halves the tile to double grid size (occupancy was grid-limited at 1.5 blk/CU).
struct Seg { const u16* A; const u16* B; int ldA; int ldB; int nkt; };

template<int NS, int BN>
__device__ __forceinline__ void gemm_core(const Seg (&segs)[NS], int rowBase, int colBase,
                                          u16* ldsA, u16* ldsB, f32x4_t (&acc)[4][BN / 32]) {
    constexpr int NACC = BN / 32;        // 2 or 4 col fragments per wave
    constexpr int NBC  = BN / 8;         // B chunks (8 rows each)
    constexpr int PER  = (16 + NBC) / 4; // chunk loads per wave: 6 (BN=64) or 8 (BN=128)
    const int t = threadIdx.x;
    const int lane = t & 63, wave = t >> 6;
    const int wR = (wave >> 1) * 64, wC = (wave & 1) * (BN / 2);
    const int l15 = lane & 15, lk = (lane >> 4) * 8;
    const int sr = lane >> 3;            // row within 8-row chunk
    const int scol = (lane & 7) * 8;     // col (bf16 elems) within row
#pragma unroll
    for (int s = 0; s < NS; ++s) {
        const u16* Ag = segs[s].A + (size_t)rowBase * segs[s].ldA;
        const u16* Bg = segs[s].B + (size_t)colBase * segs[s].ldB;
        const int ldA = segs[s].ldA, ldB = segs[s].ldB, nkt = segs[s].nkt;
        for (int kt = 0; kt < nkt; ++kt) {
            __syncthreads();   // previous compute done before LDS overwrite
#pragma unroll
            for (int i = 0; i < PER; ++i) {
                int ci = wave * PER + i;   // chunk: 8 rows = 1024 B (64 lanes x 16 B)
                if (ci < 16) {
                    int r = ci * 8 + sr;
                    gload_lds16(Ag + (size_t)r * ldA + kt * 64 + scol, ldsA + ci * 512);
                } else {
                    int cb = ci - 16;
                    int r = cb * 8 + sr;
                    gload_lds16(Bg + (size_t)r * ldB + kt * 64 + scol, ldsB + cb * 512);
                }
            }
            __syncthreads();   // barrier drains vmcnt -> LDS tiles complete
#pragma unroll
            for (int kk = 0; kk < 2; ++kk) {
                bf16x8_t a[4], b[NACC];
#pragma unroll
                for (int m = 0; m < 4; ++m)
                    a[m] = *(const bf16x8_t*)(ldsA + (wR + m * 16 + l15) * 64 + kk * 32 + lk);
#pragma unroll
                for (int n = 0; n < NACC; ++n)
                    b[n] = *(const bf16x8_t*)(ldsB + (wC + n * 16 + l15) * 64 + kk * 32 + lk);
#pragma unroll
                for (int m = 0; m < 4; ++m)
#pragma unroll
                    for (int n = 0; n < NACC; ++n)
                        acc[m][n] = __builtin_amdgcn_mfma_f32_16x16x32_bf16(a[m], b[n], acc[m][n], 0, 0, 0);
            }
        }
    }
}

// block-id decode; optional bijective XCD swizzle (m204): contiguous wg chunks per XCD,
// col fastest -> col-blocks sharing an A-panel co-resident on one XCD's L2.
template<int NCOL, int NROW, int NWG, bool SWZ>
__device__ __forceinline__ void decode_wg(int o, int& col, int& row, int& kz) {
    int wg = o;
    if (SWZ) {
        constexpr int q = NWG / 8, r = NWG % 8;
        int xcd = o & 7, idx = o >> 3;
        wg = (xcd < r ? xcd * (q + 1) : r * (q + 1) + (xcd - r) * q) + idx;
    }
    col = wg % NCOL; int tmp = wg / NCOL; row = tmp % NROW; kz = tmp / NROW;
}

#define GEMM_PRE(BN, NCOL, NROW, NWG, SWZ)                                 \
    __shared__ u16 ldsA[128 * 64];                                         \
    __shared__ u16 ldsB[BN * 64];                                          \
    int col_, row_, kz_;                                                   \
    decode_wg<NCOL, NROW, NWG, SWZ>(blockIdx.x, col_, row_, kz_);          \
    int rowBase = row_ * 128, colBase = col_ * BN;                         \
    f32x4_t acc[4][BN / 32];                                               \
    _Pragma("unroll") for (int m = 0; m < 4; ++m)                          \
        _Pragma("unroll") for (int n = 0; n < BN / 32; ++n)                \
            acc[m][n] = (f32x4_t){0.f, 0.f, 0.f, 0.f};

#define EPI_IDX(BN)                                                        \
    const int lane = threadIdx.x & 63, wave = threadIdx.x >> 6;            \
    const int wR = (wave >> 1) * 64, wC = (wave & 1) * (BN / 2);           \
    const int l15 = lane & 15, r4 = (lane >> 4) * 4;

// z-GEMM: g = sigmoid(x@Wk + h0@Wr + bias) -> gbuf bf16 (4096 x 3072)
__global__ __launch_bounds__(256) void k_gemm1(const u16* xb, const u16* h0b,
                                               const u16* kT, const u16* rkT,
                                               const float* __restrict__ bias,
                                               u16* __restrict__ gbuf) {
    GEMM_PRE(128, 24, 32, 768, false);
    Seg segs[2] = { { xb, kT, INF, INF, INF / 64 },
                    { h0b, rkT, UNITS_, UNITS_, UNITS_ / 64 } };
    gemm_core<2, 128>(segs, rowBase, colBase, ldsA, ldsB, acc);
    EPI_IDX(128);
#pragma unroll
    for (int m = 0; m < 4; ++m)
#pragma unroll
        for (int n = 0; n < 4; ++n)
#pragma unroll
            for (int j = 0; j < 4; ++j) {
                int row = rowBase + wR + m * 16 + r4 + j;
                int col = colBase + wC + n * 16 + l15;
                gbuf[(size_t)row * 3072 + col] = f2bf(sigm(acc[m][n][j] + bias[col]));
            }
}

// agg GEMM: agg[k] = x@ski[k] + ss[k]@sks[k]  -> f32 (3 x 4096 x 512)
__global__ __launch_bounds__(256) void k_gemm2(const u16* xb, const u16* ssb,
                                               const u16* skiT, const u16* sksT,
                                               float* __restrict__ agg) {
    GEMM_PRE(64, 8, 32, 768, false);
    int k = kz_;
    Seg segs[2] = { { xb, skiT + (size_t)k * SUBD * INF, INF, INF, INF / 64 },
                    { ssb + (size_t)k * B_DIM * SUBD, sksT + (size_t)k * SUBD * SUBD, SUBD, SUBD, SUBD / 64 } };
    gemm_core<2, 64>(segs, rowBase, colBase, ldsA, ldsB, acc);
    EPI_IDX(64);
#pragma unroll
    for (int m = 0; m < 4; ++m)
#pragma unroll
        for (int n = 0; n < 2; ++n)
#pragma unroll
            for (int j = 0; j < 4; ++j) {
                int row = rowBase + wR + m * 16 + r4 + j;
                int col = colBase + wC + n * 16 + l15;
                agg[((size_t)k * B_DIM + row) * SUBD + col] = acc[m][n][j];
            }
}

// sub_out GEMM: silu(agg)@bw^T + bases@ssw^T; epilogue -> new_sub_states (f32 out) + subflat bf16
__global__ __launch_bounds__(256) void k_gemm3(const u16* silu, const u16* bases,
                                               const u16* bwb, const u16* sswb,
                                               const float* __restrict__ srk,
                                               const float* __restrict__ ss,
                                               float* __restrict__ nss_out,
                                               u16* __restrict__ subfl) {
    GEMM_PRE(64, 8, 32, 768, true);   // XCD swizzle: col-blocks of a row-panel share one XCD L2
    int k = kz_;
    Seg segs[2] = { { silu + (size_t)k * B_DIM * SUBD, bwb + (size_t)k * SUBD * SUBD, SUBD, SUBD, SUBD / 64 },
                    { bases + (size_t)k * B_DIM * G3K, sswb + (size_t)k * SUBD * G3K, G3K, G3K, G3K / 64 } };
    gemm_core<2, 64>(segs, rowBase, colBase, ldsA, ldsB, acc);
    EPI_IDX(64);
#pragma unroll
    for (int m = 0; m < 4; ++m)
#pragma unroll
        for (int n = 0; n < 2; ++n)
#pragma unroll
            for (int j = 0; j < 4; ++j) {
                int row = rowBase + wR + m * 16 + r4 + j;
                int col = colBase + wC + n * 16 + l15;
                float so = acc[m][n][j];
                float rh = srk[k * 1024 + col];
                float rx = srk[k * 1024 + 512 + col];
                size_t o = ((size_t)k * B_DIM + row) * SUBD + col;
                nss_out[o] = rh * so + rx * ss[o];
                subfl[(size_t)row * 1536 + k * SUBD + col] = f2bf(so);
            }
}

// output GEMM: h = sigmoid(subflat@aw + ab) * tanh(c_new)
__global__ __launch_bounds__(256) void k_gemm4(const u16* subfl, const u16* awT,
                                               const float* __restrict__ abias,
                                               const float* __restrict__ c_new,
                                               float* __restrict__ h_out) {
    GEMM_PRE(64, 16, 32, 512, false);
    Seg segs[1] = { { subfl, awT, 1536, 1536, 1536 / 64 } };
    gemm_core<1, 64>(segs, rowBase, colBase, ldsA, ldsB, acc);
    EPI_IDX(64);
#pragma unroll
    for (int m = 0; m < 4; ++m)
#pragma unroll
        for (int n = 0; n < 2; ++n)
#pragma unroll
            for (int j = 0; j < 4; ++j) {
                int row = rowBase + wR + m * 16 + r4 + j;
                int col = colBase + wC + n * 16 + l15;
                float ov = sigm(acc[m][n][j] + abias[col]);
                h_out[(size_t)row * 1024 + col] = ov * tanh_(c_new[(size_t)row * 1024 + col]);
            }
}

// ---------------- launch ----------------
extern "C" void kernel_launch(void* const* d_in, const int* in_sizes, int n_in,
                              void* d_out, int out_size, void* d_ws, size_t ws_size,
                              hipStream_t stream) {
    const float* x    = (const float*)d_in[0];
    const float* h0   = (const float*)d_in[1];
    const float* c0   = (const float*)d_in[2];
    const float* ss   = (const float*)d_in[3];
    const float* Wk   = (const float*)d_in[4];
    const float* Wr   = (const float*)d_in[5];
    const float* bias = (const float*)d_in[6];
    const float* ski  = (const float*)d_in[7];
    const float* sks  = (const float*)d_in[8];
    const float* srk  = (const float*)d_in[9];
    const float* bw   = (const float*)d_in[10];
    const float* sw   = (const float*)d_in[11];
    const float* sc   = (const float*)d_in[12];
    const float* aw   = (const float*)d_in[13];
    const float* ab   = (const float*)d_in[14];

    float* out_h   = (float*)d_out;
    float* out_c   = out_h + (size_t)B_DIM * UNITS_;
    float* out_nss = out_c + (size_t)B_DIM * UNITS_;

    char* w = (char*)d_ws;
    auto take = [&](size_t bytes) -> char* {
        char* p = w; w += (bytes + 255) & ~(size_t)255; return p;
    };
    u16*   xb    = (u16*)take((size_t)B_DIM * INF * 2);
    u16*   h0b   = (u16*)take((size_t)B_DIM * UNITS_ * 2);
    u16*   ssb   = (u16*)take((size_t)NSUB_ * B_DIM * SUBD * 2);
    u16*   kT    = (u16*)take((size_t)3072 * INF * 2);
    u16*   rkT   = (u16*)take((size_t)3072 * UNITS_ * 2);
    u16*   skiT  = (u16*)take((size_t)NSUB_ * SUBD * INF * 2);
    u16*   sksT  = (u16*)take((size_t)NSUB_ * SUBD * SUBD * 2);
    u16*   bwb   = (u16*)take((size_t)NSUB_ * SUBD * SUBD * 2);
    u16*   sswb  = (u16*)take((size_t)NSUB_ * SUBD * G3K * 2);
    u16*   awT   = (u16*)take((size_t)UNITS_ * 1536 * 2);
    float* agg   = (float*)take((size_t)NSUB_ * B_DIM * SUBD * 4);
    u16*   siluB = (u16*)take((size_t)NSUB_ * B_DIM * SUBD * 2);
    u16*   subfl = (u16*)take((size_t)B_DIM * 1536 * 2);
    u16*   basesB= (u16*)take((size_t)NSUB_ * B_DIM * G3K * 2);
    u16*   gbuf  = basesB;   // alias: gbuf (25 MB) is dead before basesB is written

    dim3 tb(256);
    // converts
    k_f32_to_bf16<<<(B_DIM * INF / 4 + 255) / 256, tb, 0, stream>>>(x, xb, B_DIM * INF / 4);
    k_f32_to_bf16<<<(B_DIM * UNITS_ / 4 + 255) / 256, tb, 0, stream>>>(h0, h0b, B_DIM * UNITS_ / 4);
    k_f32_to_bf16<<<(NSUB_ * B_DIM * SUBD / 4 + 255) / 256, tb, 0, stream>>>(ss, ssb, NSUB_ * B_DIM * SUBD / 4);
    k_f32_to_bf16<<<(NSUB_ * SUBD * SUBD / 4 + 255) / 256, tb, 0, stream>>>(bw, bwb, NSUB_ * SUBD * SUBD / 4);
    k_ssw<<<(NSUB_ * SUBD * G3K / 4 + 255) / 256, tb, 0, stream>>>(sw, sc, sswb, NSUB_ * SUBD * G3K / 4);
    dim3 tt(32, 8);
    k_tconv<<<dim3(3072 / 32, INF / 32, 1), tt, 0, stream>>>(Wk, kT, INF, 3072, 0, 0);
    k_tconv<<<dim3(3072 / 32, UNITS_ / 32, 1), tt, 0, stream>>>(Wr, rkT, UNITS_, 3072, 0, 0);
    k_tconv<<<dim3(SUBD / 32, INF / 32, NSUB_), tt, 0, stream>>>(ski, skiT, INF, SUBD,
                                                                 (size_t)INF * SUBD, (size_t)SUBD * INF);
    k_tconv<<<dim3(SUBD / 32, SUBD / 32, NSUB_), tt, 0, stream>>>(sks, sksT, SUBD, SUBD,
                                                                  (size_t)SUBD * SUBD, (size_t)SUBD * SUBD);
    k_tconv<<<dim3(UNITS_ / 32, 1536 / 32, 1), tt, 0, stream>>>(aw, awT, 1536, UNITS_, 0, 0);

    // gate GEMM + c_new
    k_gemm1<<<768, tb, 0, stream>>>(xb, h0b, kT, rkT, bias, gbuf);
    k_gemm2<<<768, tb, 0, stream>>>(xb, ssb, skiT, sksT, agg);
    k_cnew<<<(B_DIM * UNITS_ / 4 + 255) / 256, tb, 0, stream>>>(gbuf, c0, out_c, B_DIM * UNITS_ / 4);

    // spline bases + silu (gbuf region now dead -> basesB reuse OK)
    k_bases<<<4096, tb, 0, stream>>>(agg, basesB, siluB, NSUB_ * B_DIM * SUBD);

    // sub_out GEMM (base K=512 + spline K=4096), epilogue writes new_sub_states + subflat
    k_gemm3<<<768, tb, 0, stream>>>(siluB, basesB, bwb, sswb, srk, ss, out_nss, subfl);
    // aggregation GEMM + h_new
    k_gemm4<<<512, tb, 0, stream>>>(subfl, awT, ab, out_c, out_h);
}

// Round 7
// 471.767 us; speedup vs baseline: 1.2086x; 1.0618x over previous
//
#include <hip/hip_runtime.h>

// ---------------- problem constants ----------------
#define B_DIM   4096
#define INF     512      // IN_DIM
#define UNITS_  1024
#define SUBD    512
#define NSUB_   3
#define NBAS    8        // GRID_SIZE + SPLINE_ORDER
#define G3K     (SUBD * NBAS)   // 4096 spline reduction dim

typedef __attribute__((ext_vector_type(8))) short bf16x8_t;   // 8 bf16 (4 VGPR)
typedef __attribute__((ext_vector_type(4))) float f32x4_t;    // MFMA acc
typedef unsigned short u16;

__device__ __forceinline__ u16 f2bf(float f) {
    union { float f; unsigned int u; } v; v.f = f;
    unsigned int r = v.u + 0x7fffu + ((v.u >> 16) & 1u);   // RNE
    return (u16)(r >> 16);
}
__device__ __forceinline__ float bf2f(u16 h) {
    union { unsigned int u; float f; } v; v.u = ((unsigned int)h) << 16;
    return v.f;
}
__device__ __forceinline__ float sigm(float x) { return 1.0f / (1.0f + __expf(-x)); }
__device__ __forceinline__ float tanh_(float x) {
    float e = __expf(2.0f * x);
    return 1.0f - 2.0f / (e + 1.0f);
}

// async global->LDS, 16B per lane. LDS dest must be wave-uniform base (+lane*16 implicit).
__device__ __forceinline__ void gload_lds16(const void* g, void* l) {
    __builtin_amdgcn_global_load_lds(
        (const __attribute__((address_space(1))) unsigned int*)g,
        (__attribute__((address_space(3))) unsigned int*)l, 16, 0, 0);
}

// ---------------- elementwise converts ----------------
__global__ void k_f32_to_bf16(const float* __restrict__ in, u16* __restrict__ out, int n4) {
    int i = blockIdx.x * blockDim.x + threadIdx.x;
    if (i >= n4) return;
    float4 v = ((const float4*)in)[i];
    ushort4 r; r.x = f2bf(v.x); r.y = f2bf(v.y); r.z = f2bf(v.z); r.w = f2bf(v.w);
    ((ushort4*)out)[i] = r;
}

// scaled spline weight: out = bf16(sw * scaler[idx>>3])
__global__ void k_ssw(const float* __restrict__ sw, const float* __restrict__ sc,
                      u16* __restrict__ out, int n4) {
    int i = blockIdx.x * blockDim.x + threadIdx.x;
    if (i >= n4) return;
    float4 v = ((const float4*)sw)[i];
    float s = sc[i >> 1];                  // (i*4)>>3 == i>>1 (4-vec never crosses the 8-group)
    ushort4 r; r.x = f2bf(v.x * s); r.y = f2bf(v.y * s); r.z = f2bf(v.z * s); r.w = f2bf(v.w * s);
    ((ushort4*)out)[i] = r;
}

// transpose + convert: out[C][R] bf16 = in[R][C] f32.  block (32,8), grid (C/32, R/32, batch)
__global__ void k_tconv(const float* __restrict__ in, u16* __restrict__ out,
                        int R, int C, size_t inStride, size_t outStride) {
    in  += (size_t)blockIdx.z * inStride;
    out += (size_t)blockIdx.z * outStride;
    __shared__ float tile[32][33];
    int c0 = blockIdx.x * 32, r0 = blockIdx.y * 32;
    int tx = threadIdx.x, ty = threadIdx.y;
#pragma unroll
    for (int j = 0; j < 4; ++j)
        tile[ty + j * 8][tx] = in[(size_t)(r0 + ty + j * 8) * C + c0 + tx];
    __syncthreads();
#pragma unroll
    for (int j = 0; j < 4; ++j)
        out[(size_t)(c0 + ty + j * 8) * R + r0 + tx] = f2bf(tile[tx][ty + j * 8]);
}

// c_new = f*c0 + i*tanh(c_gate), gates already sigmoided (bf16 in gbuf, cols [i|f|c])
__global__ void k_cnew(const u16* __restrict__ gbuf, const float* __restrict__ c0,
                       float* __restrict__ c_out, int n4) {
    int i = blockIdx.x * blockDim.x + threadIdx.x;
    if (i >= n4) return;
    int u4 = i * 4;
    int b = u4 >> 10, u = u4 & 1023;
    const u16* gr = gbuf + (size_t)b * 3072 + u;
    ushort4 gi = *(const ushort4*)gr;
    ushort4 gf = *(const ushort4*)(gr + 1024);
    ushort4 gc = *(const ushort4*)(gr + 2048);
    float4 c0v = ((const float4*)c0)[i];
    float4 r;
    r.x = bf2f(gf.x) * c0v.x + bf2f(gi.x) * tanh_(bf2f(gc.x));
    r.y = bf2f(gf.y) * c0v.y + bf2f(gi.y) * tanh_(bf2f(gc.y));
    r.z = bf2f(gf.z) * c0v.z + bf2f(gi.z) * tanh_(bf2f(gc.z));
    r.w = bf2f(gf.w) * c0v.w + bf2f(gi.w) * tanh_(bf2f(gc.w));
    ((float4*)c_out)[i] = r;
}

// per agg element: silu (bf16) and the 8 cubic B-spline bases (bf16x8, one 16B store)
// knots t_j = (j-3)*1.2 - 3, j = 0..11  (exactly the reference make_grid formula)
__global__ void k_bases(const float* __restrict__ agg, u16* __restrict__ bases,
                        u16* __restrict__ silu, int n) {
    for (int i = blockIdx.x * blockDim.x + threadIdx.x; i < n; i += gridDim.x * blockDim.x) {
        float x = agg[i];
        silu[i] = f2bf(x * sigm(x));
        float b[11];
#pragma unroll
        for (int j = 0; j < 11; ++j) {
            float tj  = 1.2f * (float)(j - 3) - 3.0f;
            float tj1 = 1.2f * (float)(j - 2) - 3.0f;
            b[j] = (x >= tj && x < tj1) ? 1.0f : 0.0f;
        }
#pragma unroll
        for (int k = 1; k <= 3; ++k) {
            float inv = 1.0f / (1.2f * (float)k);
#pragma unroll
            for (int j = 0; j < 11; ++j) {
                if (j > 10 - k) break;
                float tj   = 1.2f * (float)(j - 3) - 3.0f;
                float tjk1 = 1.2f * (float)(j + k - 2) - 3.0f;   // t_{j+k+1}
                b[j] = (x - tj) * inv * b[j] + (tjk1 - x) * inv * b[j + 1];
            }
        }
        bf16x8_t v;
#pragma unroll
        for (int j = 0; j < 8; ++j) v[j] = (short)f2bf(b[j]);
        *(bf16x8_t*)(bases + (size_t)i * 8) = v;
    }
}

// ---------------- MFMA GEMM core ----------------
// 128xBN tile, BK=64, 4 waves / 256 threads, B^T operands.
// Prefetch double-buffer (T3-minimum): stage(kt+1 -> back buffer) issued BEFORE
// compute(kt); the single __syncthreads() per K-step drains vmcnt AFTER compute,
// so next-tile loads overlap ds_read+MFMA. One barrier per K-step (was two).
struct Seg { const u16* A; const u16* B; int ldA; int ldB; int nkt; };

template<int NS, int BN>
__device__ __forceinline__ void gemm_core(const Seg (&segs)[NS], int rowBase, int colBase,
                                          u16* lds, f32x4_t (&acc)[4][BN / 32]) {
    constexpr int NACC = BN / 32;        // col fragments per wave
    constexpr int NBC  = BN / 8;         // B chunks (8 rows each)
    constexpr int PER  = (16 + NBC) / 4; // chunk loads per wave
    constexpr int AELE = 128 * 64;       // A tile elems
    constexpr int BELE = BN * 64;        // B tile elems
    constexpr int BUF  = AELE + BELE;    // one buffer
    const int t = threadIdx.x;
    const int lane = t & 63, wave = t >> 6;
    const int wR = (wave >> 1) * 64, wC = (wave & 1) * (BN / 2);
    const int l15 = lane & 15, lk = (lane >> 4) * 8;
    const int sr = lane >> 3;            // row within 8-row chunk
    const int scol = (lane & 7) * 8;     // col (bf16 elems) within row

    int NT = 0;
#pragma unroll
    for (int s = 0; s < NS; ++s) NT += segs[s].nkt;

    auto stage = [&](int kt, int buf) {
        const u16* Ag; const u16* Bg; int ldA, ldB, kl = kt;
        if (NS == 1 || kt < segs[0].nkt) {
            Ag = segs[0].A; Bg = segs[0].B; ldA = segs[0].ldA; ldB = segs[0].ldB;
        } else {
            Ag = segs[NS - 1].A; Bg = segs[NS - 1].B;
            ldA = segs[NS - 1].ldA; ldB = segs[NS - 1].ldB;
            kl = kt - segs[0].nkt;
        }
        const u16* As = Ag + (size_t)rowBase * ldA + kl * 64 + scol;
        const u16* Bs = Bg + (size_t)colBase * ldB + kl * 64 + scol;
        u16* dA = lds + buf * BUF;
        u16* dB = dA + AELE;
#pragma unroll
        for (int i = 0; i < PER; ++i) {
            int ci = wave * PER + i;     // chunk: 8 rows = 1024 B (64 lanes x 16 B)
            if (ci < 16) {
                gload_lds16(As + (size_t)(ci * 8 + sr) * ldA, dA + ci * 512);
            } else {
                int cb = ci - 16;
                gload_lds16(Bs + (size_t)(cb * 8 + sr) * ldB, dB + cb * 512);
            }
        }
    };

    stage(0, 0);
    __syncthreads();                     // buf0 ready
    int cur = 0;
    for (int kt = 0; kt < NT; ++kt) {
        if (kt + 1 < NT) stage(kt + 1, cur ^ 1);   // issue loads into back buffer
        const u16* lA = lds + cur * BUF;
        const u16* lB = lA + AELE;
#pragma unroll
        for (int kk = 0; kk < 2; ++kk) {
            bf16x8_t a[4], b[NACC];
#pragma unroll
            for (int m = 0; m < 4; ++m)
                a[m] = *(const bf16x8_t*)(lA + (wR + m * 16 + l15) * 64 + kk * 32 + lk);
#pragma unroll
            for (int n = 0; n < NACC; ++n)
                b[n] = *(const bf16x8_t*)(lB + (wC + n * 16 + l15) * 64 + kk * 32 + lk);
#pragma unroll
            for (int m = 0; m < 4; ++m)
#pragma unroll
                for (int n = 0; n < NACC; ++n)
                    acc[m][n] = __builtin_amdgcn_mfma_f32_16x16x32_bf16(a[m], b[n], acc[m][n], 0, 0, 0);
        }
        __syncthreads();                 // drains vmcnt AFTER compute: overlap achieved
        cur ^= 1;
    }
}

// block-id decode; optional bijective XCD swizzle (m204): contiguous wg chunks per XCD,
// col fastest -> col-blocks sharing an A-panel co-resident on one XCD's L2.
template<int NCOL, int NROW, int NWG, bool SWZ>
__device__ __forceinline__ void decode_wg(int o, int& col, int& row, int& kz) {
    int wg = o;
    if (SWZ) {
        constexpr int q = NWG / 8, r = NWG % 8;
        int xcd = o & 7, idx = o >> 3;
        wg = (xcd < r ? xcd * (q + 1) : r * (q + 1) + (xcd - r) * q) + idx;
    }
    col = wg % NCOL; int tmp = wg / NCOL; row = tmp % NROW; kz = tmp / NROW;
}

#define GEMM_PRE(BN, NCOL, NROW, NWG, SWZ)                                 \
    __shared__ u16 lds[2 * (128 * 64 + BN * 64)];                          \
    int col_, row_, kz_;                                                   \
    decode_wg<NCOL, NROW, NWG, SWZ>(blockIdx.x, col_, row_, kz_);          \
    int rowBase = row_ * 128, colBase = col_ * BN;                         \
    f32x4_t acc[4][BN / 32];                                               \
    _Pragma("unroll") for (int m = 0; m < 4; ++m)                          \
        _Pragma("unroll") for (int n = 0; n < BN / 32; ++n)                \
            acc[m][n] = (f32x4_t){0.f, 0.f, 0.f, 0.f};

#define EPI_IDX(BN)                                                        \
    const int lane = threadIdx.x & 63, wave = threadIdx.x >> 6;            \
    const int wR = (wave >> 1) * 64, wC = (wave & 1) * (BN / 2);           \
    const int l15 = lane & 15, r4 = (lane >> 4) * 4;

// z-GEMM: g = sigmoid(x@Wk + h0@Wr + bias) -> gbuf bf16 (4096 x 3072)
__global__ __launch_bounds__(256) void k_gemm1(const u16* xb, const u16* h0b,
                                               const u16* kT, const u16* rkT,
                                               const float* __restrict__ bias,
                                               u16* __restrict__ gbuf) {
    GEMM_PRE(64, 48, 32, 1536, false);
    Seg segs[2] = { { xb, kT, INF, INF, INF / 64 },
                    { h0b, rkT, UNITS_, UNITS_, UNITS_ / 64 } };
    gemm_core<2, 64>(segs, rowBase, colBase, lds, acc);
    EPI_IDX(64);
#pragma unroll
    for (int m = 0; m < 4; ++m)
#pragma unroll
        for (int n = 0; n < 2; ++n)
#pragma unroll
            for (int j = 0; j < 4; ++j) {
                int row = rowBase + wR + m * 16 + r4 + j;
                int col = colBase + wC + n * 16 + l15;
                gbuf[(size_t)row * 3072 + col] = f2bf(sigm(acc[m][n][j] + bias[col]));
            }
}

// agg GEMM: agg[k] = x@ski[k] + ss[k]@sks[k]  -> f32 (3 x 4096 x 512)
__global__ __launch_bounds__(256) void k_gemm2(const u16* xb, const u16* ssb,
                                               const u16* skiT, const u16* sksT,
                                               float* __restrict__ agg) {
    GEMM_PRE(64, 8, 32, 768, false);
    int k = kz_;
    Seg segs[2] = { { xb, skiT + (size_t)k * SUBD * INF, INF, INF, INF / 64 },
                    { ssb + (size_t)k * B_DIM * SUBD, sksT + (size_t)k * SUBD * SUBD, SUBD, SUBD, SUBD / 64 } };
    gemm_core<2, 64>(segs, rowBase, colBase, lds, acc);
    EPI_IDX(64);
#pragma unroll
    for (int m = 0; m < 4; ++m)
#pragma unroll
        for (int n = 0; n < 2; ++n)
#pragma unroll
            for (int j = 0; j < 4; ++j) {
                int row = rowBase + wR + m * 16 + r4 + j;
                int col = colBase + wC + n * 16 + l15;
                agg[((size_t)k * B_DIM + row) * SUBD + col] = acc[m][n][j];
            }
}

// sub_out GEMM: silu(agg)@bw^T + bases@ssw^T; epilogue -> new_sub_states (f32 out) + subflat bf16
__global__ __launch_bounds__(256) void k_gemm3(const u16* silu, const u16* bases,
                                               const u16* bwb, const u16* sswb,
                                               const float* __restrict__ srk,
                                               const float* __restrict__ ss,
                                               float* __restrict__ nss_out,
                                               u16* __restrict__ subfl) {
    GEMM_PRE(64, 8, 32, 768, true);   // XCD swizzle: col-blocks of a row-panel share one XCD L2
    int k = kz_;
    Seg segs[2] = { { silu + (size_t)k * B_DIM * SUBD, bwb + (size_t)k * SUBD * SUBD, SUBD, SUBD, SUBD / 64 },
                    { bases + (size_t)k * B_DIM * G3K, sswb + (size_t)k * SUBD * G3K, G3K, G3K, G3K / 64 } };
    gemm_core<2, 64>(segs, rowBase, colBase, lds, acc);
    EPI_IDX(64);
#pragma unroll
    for (int m = 0; m < 4; ++m)
#pragma unroll
        for (int n = 0; n < 2; ++n)
#pragma unroll
            for (int j = 0; j < 4; ++j) {
                int row = rowBase + wR + m * 16 + r4 + j;
                int col = colBase + wC + n * 16 + l15;
                float so = acc[m][n][j];
                float rh = srk[k * 1024 + col];
                float rx = srk[k * 1024 + 512 + col];
                size_t o = ((size_t)k * B_DIM + row) * SUBD + col;
                nss_out[o] = rh * so + rx * ss[o];
                subfl[(size_t)row * 1536 + k * SUBD + col] = f2bf(so);
            }
}

// output GEMM: h = sigmoid(subflat@aw + ab) * tanh(c_new)
__global__ __launch_bounds__(256) void k_gemm4(const u16* subfl, const u16* awT,
                                               const float* __restrict__ abias,
                                               const float* __restrict__ c_new,
                                               float* __restrict__ h_out) {
    GEMM_PRE(64, 16, 32, 512, false);
    Seg segs[1] = { { subfl, awT, 1536, 1536, 1536 / 64 } };
    gemm_core<1, 64>(segs, rowBase, colBase, lds, acc);
    EPI_IDX(64);
#pragma unroll
    for (int m = 0; m < 4; ++m)
#pragma unroll
        for (int n = 0; n < 2; ++n)
#pragma unroll
            for (int j = 0; j < 4; ++j) {
                int row = rowBase + wR + m * 16 + r4 + j;
                int col = colBase + wC + n * 16 + l15;
                float ov = sigm(acc[m][n][j] + abias[col]);
                h_out[(size_t)row * 1024 + col] = ov * tanh_(c_new[(size_t)row * 1024 + col]);
            }
}

// ---------------- launch ----------------
extern "C" void kernel_launch(void* const* d_in, const int* in_sizes, int n_in,
                              void* d_out, int out_size, void* d_ws, size_t ws_size,
                              hipStream_t stream) {
    const float* x    = (const float*)d_in[0];
    const float* h0   = (const float*)d_in[1];
    const float* c0   = (const float*)d_in[2];
    const float* ss   = (const float*)d_in[3];
    const float* Wk   = (const float*)d_in[4];
    const float* Wr   = (const float*)d_in[5];
    const float* bias = (const float*)d_in[6];
    const float* ski  = (const float*)d_in[7];
    const float* sks  = (const float*)d_in[8];
    const float* srk  = (const float*)d_in[9];
    const float* bw   = (const float*)d_in[10];
    const float* sw   = (const float*)d_in[11];
    const float* sc   = (const float*)d_in[12];
    const float* aw   = (const float*)d_in[13];
    const float* ab   = (const float*)d_in[14];

    float* out_h   = (float*)d_out;
    float* out_c   = out_h + (size_t)B_DIM * UNITS_;
    float* out_nss = out_c + (size_t)B_DIM * UNITS_;

    char* w = (char*)d_ws;
    auto take = [&](size_t bytes) -> char* {
        char* p = w; w += (bytes + 255) & ~(size_t)255; return p;
    };
    u16*   xb    = (u16*)take((size_t)B_DIM * INF * 2);
    u16*   h0b   = (u16*)take((size_t)B_DIM * UNITS_ * 2);
    u16*   ssb   = (u16*)take((size_t)NSUB_ * B_DIM * SUBD * 2);
    u16*   kT    = (u16*)take((size_t)3072 * INF * 2);
    u16*   rkT   = (u16*)take((size_t)3072 * UNITS_ * 2);
    u16*   skiT  = (u16*)take((size_t)NSUB_ * SUBD * INF * 2);
    u16*   sksT  = (u16*)take((size_t)NSUB_ * SUBD * SUBD * 2);
    u16*   bwb   = (u16*)take((size_t)NSUB_ * SUBD * SUBD * 2);
    u16*   sswb  = (u16*)take((size_t)NSUB_ * SUBD * G3K * 2);
    u16*   awT   = (u16*)take((size_t)UNITS_ * 1536 * 2);
    float* agg   = (float*)take((size_t)NSUB_ * B_DIM * SUBD * 4);
    u16*   siluB = (u16*)take((size_t)NSUB_ * B_DIM * SUBD * 2);
    u16*   subfl = (u16*)take((size_t)B_DIM * 1536 * 2);
    u16*   basesB= (u16*)take((size_t)NSUB_ * B_DIM * G3K * 2);
    u16*   gbuf  = basesB;   // alias: gbuf (25 MB) is dead before basesB is written

    dim3 tb(256);
    // converts
    k_f32_to_bf16<<<(B_DIM * INF / 4 + 255) / 256, tb, 0, stream>>>(x, xb, B_DIM * INF / 4);
    k_f32_to_bf16<<<(B_DIM * UNITS_ / 4 + 255) / 256, tb, 0, stream>>>(h0, h0b, B_DIM * UNITS_ / 4);
    k_f32_to_bf16<<<(NSUB_ * B_DIM * SUBD / 4 + 255) / 256, tb, 0, stream>>>(ss, ssb, NSUB_ * B_DIM * SUBD / 4);
    k_f32_to_bf16<<<(NSUB_ * SUBD * SUBD / 4 + 255) / 256, tb, 0, stream>>>(bw, bwb, NSUB_ * SUBD * SUBD / 4);
    k_ssw<<<(NSUB_ * SUBD * G3K / 4 + 255) / 256, tb, 0, stream>>>(sw, sc, sswb, NSUB_ * SUBD * G3K / 4);
    dim3 tt(32, 8);
    k_tconv<<<dim3(3072 / 32, INF / 32, 1), tt, 0, stream>>>(Wk, kT, INF, 3072, 0, 0);
    k_tconv<<<dim3(3072 / 32, UNITS_ / 32, 1), tt, 0, stream>>>(Wr, rkT, UNITS_, 3072, 0, 0);
    k_tconv<<<dim3(SUBD / 32, INF / 32, NSUB_), tt, 0, stream>>>(ski, skiT, INF, SUBD,
                                                                 (size_t)INF * SUBD, (size_t)SUBD * INF);
    k_tconv<<<dim3(SUBD / 32, SUBD / 32, NSUB_), tt, 0, stream>>>(sks, sksT, SUBD, SUBD,
                                                                  (size_t)SUBD * SUBD, (size_t)SUBD * SUBD);
    k_tconv<<<dim3(UNITS_ / 32, 1536 / 32, 1), tt, 0, stream>>>(aw, awT, 1536, UNITS_, 0, 0);

    // gate GEMM + c_new
    k_gemm1<<<1536, tb, 0, stream>>>(xb, h0b, kT, rkT, bias, gbuf);
    k_gemm2<<<768, tb, 0, stream>>>(xb, ssb, skiT, sksT, agg);
    k_cnew<<<(B_DIM * UNITS_ / 4 + 255) / 256, tb, 0, stream>>>(gbuf, c0, out_c, B_DIM * UNITS_ / 4);

    // spline bases + silu (gbuf region now dead -> basesB reuse OK)
    k_bases<<<4096, tb, 0, stream>>>(agg, basesB, siluB, NSUB_ * B_DIM * SUBD);

    // sub_out GEMM (base K=512 + spline K=4096), epilogue writes new_sub_states + subflat
    k_gemm3<<<768, tb, 0, stream>>>(siluB, basesB, bwb, sswb, srk, ss, out_nss, subfl);
    // aggregation GEMM + h_new
    k_gemm4<<<512, tb, 0, stream>>>(subfl, awT, ab, out_c, out_h);
}

// Round 8
// 445.329 us; speedup vs baseline: 1.2804x; 1.0594x over previous
//
#include <hip/hip_runtime.h>

// ---------------- problem constants ----------------
#define B_DIM   4096
#define INF     512      // IN_DIM
#define UNITS_  1024
#define SUBD    512
#define NSUB_   3
#define NBAS    8        // GRID_SIZE + SPLINE_ORDER
#define G3K     (SUBD * NBAS)   // 4096 spline reduction dim

typedef __attribute__((ext_vector_type(8))) short bf16x8_t;   // 8 bf16 (4 VGPR)
typedef __attribute__((ext_vector_type(4))) float f32x4_t;    // MFMA acc
typedef unsigned short u16;

__device__ __forceinline__ u16 f2bf(float f) {
    union { float f; unsigned int u; } v; v.f = f;
    unsigned int r = v.u + 0x7fffu + ((v.u >> 16) & 1u);   // RNE
    return (u16)(r >> 16);
}
__device__ __forceinline__ float bf2f(u16 h) {
    union { unsigned int u; float f; } v; v.u = ((unsigned int)h) << 16;
    return v.f;
}
__device__ __forceinline__ float sigm(float x) { return 1.0f / (1.0f + __expf(-x)); }
__device__ __forceinline__ float tanh_(float x) {
    float e = __expf(2.0f * x);
    return 1.0f - 2.0f / (e + 1.0f);
}

// async global->LDS, 16B per lane. LDS dest must be wave-uniform base (+lane*16 implicit).
__device__ __forceinline__ void gload_lds16(const void* g, void* l) {
    __builtin_amdgcn_global_load_lds(
        (const __attribute__((address_space(1))) unsigned int*)g,
        (__attribute__((address_space(3))) unsigned int*)l, 16, 0, 0);
}

// ---------------- elementwise converts ----------------
__global__ void k_f32_to_bf16(const float* __restrict__ in, u16* __restrict__ out, int n4) {
    int i = blockIdx.x * blockDim.x + threadIdx.x;
    if (i >= n4) return;
    float4 v = ((const float4*)in)[i];
    ushort4 r; r.x = f2bf(v.x); r.y = f2bf(v.y); r.z = f2bf(v.z); r.w = f2bf(v.w);
    ((ushort4*)out)[i] = r;
}

// scaled spline weight: out = bf16(sw * scaler[idx>>3])
__global__ void k_ssw(const float* __restrict__ sw, const float* __restrict__ sc,
                      u16* __restrict__ out, int n4) {
    int i = blockIdx.x * blockDim.x + threadIdx.x;
    if (i >= n4) return;
    float4 v = ((const float4*)sw)[i];
    float s = sc[i >> 1];                  // (i*4)>>3 == i>>1 (4-vec never crosses the 8-group)
    ushort4 r; r.x = f2bf(v.x * s); r.y = f2bf(v.y * s); r.z = f2bf(v.z * s); r.w = f2bf(v.w * s);
    ((ushort4*)out)[i] = r;
}

// transpose + convert: out[C][R] bf16 = in[R][C] f32.  block (32,8), grid (C/32, R/32, batch)
__global__ void k_tconv(const float* __restrict__ in, u16* __restrict__ out,
                        int R, int C, size_t inStride, size_t outStride) {
    in  += (size_t)blockIdx.z * inStride;
    out += (size_t)blockIdx.z * outStride;
    __shared__ float tile[32][33];
    int c0 = blockIdx.x * 32, r0 = blockIdx.y * 32;
    int tx = threadIdx.x, ty = threadIdx.y;
#pragma unroll
    for (int j = 0; j < 4; ++j)
        tile[ty + j * 8][tx] = in[(size_t)(r0 + ty + j * 8) * C + c0 + tx];
    __syncthreads();
#pragma unroll
    for (int j = 0; j < 4; ++j)
        out[(size_t)(c0 + ty + j * 8) * R + r0 + tx] = f2bf(tile[tx][ty + j * 8]);
}

// c_new = f*c0 + i*tanh(c_gate), gates already sigmoided (bf16 in gbuf, cols [i|f|c])
__global__ void k_cnew(const u16* __restrict__ gbuf, const float* __restrict__ c0,
                       float* __restrict__ c_out, int n4) {
    int i = blockIdx.x * blockDim.x + threadIdx.x;
    if (i >= n4) return;
    int u4 = i * 4;
    int b = u4 >> 10, u = u4 & 1023;
    const u16* gr = gbuf + (size_t)b * 3072 + u;
    ushort4 gi = *(const ushort4*)gr;
    ushort4 gf = *(const ushort4*)(gr + 1024);
    ushort4 gc = *(const ushort4*)(gr + 2048);
    float4 c0v = ((const float4*)c0)[i];
    float4 r;
    r.x = bf2f(gf.x) * c0v.x + bf2f(gi.x) * tanh_(bf2f(gc.x));
    r.y = bf2f(gf.y) * c0v.y + bf2f(gi.y) * tanh_(bf2f(gc.y));
    r.z = bf2f(gf.z) * c0v.z + bf2f(gi.z) * tanh_(bf2f(gc.z));
    r.w = bf2f(gf.w) * c0v.w + bf2f(gi.w) * tanh_(bf2f(gc.w));
    ((float4*)c_out)[i] = r;
}

// per agg element: silu (bf16) and the 8 cubic B-spline bases (bf16x8, one 16B store)
// knots t_j = (j-3)*1.2 - 3, j = 0..11  (exactly the reference make_grid formula)
__global__ void k_bases(const float* __restrict__ agg, u16* __restrict__ bases,
                        u16* __restrict__ silu, int n) {
    for (int i = blockIdx.x * blockDim.x + threadIdx.x; i < n; i += gridDim.x * blockDim.x) {
        float x = agg[i];
        silu[i] = f2bf(x * sigm(x));
        float b[11];
#pragma unroll
        for (int j = 0; j < 11; ++j) {
            float tj  = 1.2f * (float)(j - 3) - 3.0f;
            float tj1 = 1.2f * (float)(j - 2) - 3.0f;
            b[j] = (x >= tj && x < tj1) ? 1.0f : 0.0f;
        }
#pragma unroll
        for (int k = 1; k <= 3; ++k) {
            float inv = 1.0f / (1.2f * (float)k);
#pragma unroll
            for (int j = 0; j < 11; ++j) {
                if (j > 10 - k) break;
                float tj   = 1.2f * (float)(j - 3) - 3.0f;
                float tjk1 = 1.2f * (float)(j + k - 2) - 3.0f;   // t_{j+k+1}
                b[j] = (x - tj) * inv * b[j] + (tjk1 - x) * inv * b[j + 1];
            }
        }
        bf16x8_t v;
#pragma unroll
        for (int j = 0; j < 8; ++j) v[j] = (short)f2bf(b[j]);
        *(bf16x8_t*)(bases + (size_t)i * 8) = v;
    }
}

// ---------------- MFMA GEMM core ----------------
// 128xBN tile, BK=64, 4 waves / 256 threads, B^T operands. Double-buffered LDS with
// T4 counted vmcnt: raw s_barrier + "s_waitcnt vmcnt(PER)" lets the 6 next-buffer
// loads stay in flight across barriers (full K-step of latency budget; no drain-0
// in steady state). T2 XOR swizzle (rule #21 both-sides): gload_lds dest linear,
// per-lane GLOBAL source unit = (lane&7)^(row&7); ds_read XORs unit with row&7 ->
// uniform 8 accesses/bank (was 16-way conflict on 128-B rows).
struct Seg { const u16* A; const u16* B; int ldA; int ldB; int nkt; };

template<int NS, int BN>
__device__ __forceinline__ void gemm_core(const Seg (&segs)[NS], int rowBase, int colBase,
                                          u16* lds, f32x4_t (&acc)[4][BN / 32]) {
    constexpr int NACC = BN / 32;        // col fragments per wave
    constexpr int NBC  = BN / 8;         // B chunks (8 rows each)
    constexpr int PER  = (16 + NBC) / 4; // chunk loads per wave (6 for BN=64)
    constexpr int AELE = 128 * 64;       // A tile elems
    constexpr int BELE = BN * 64;        // B tile elems
    constexpr int BUF  = AELE + BELE;    // one buffer
    const int t = threadIdx.x;
    const int lane = t & 63, wave = t >> 6;
    const int wR = (wave >> 1) * 64, wC = (wave & 1) * (BN / 2);
    const int l15 = lane & 15;
    const int sr = lane >> 3;            // row within 8-row chunk
    // T2: pre-swizzled global source unit (16B units within the 128-B row)
    const int scol = (((lane & 7) ^ (lane >> 3)) * 8);   // elems

    int NT = 0;
#pragma unroll
    for (int s = 0; s < NS; ++s) NT += segs[s].nkt;

    auto stage = [&](int kt, int buf) {
        const u16* Ag; const u16* Bg; int ldA, ldB, kl = kt;
        if (NS == 1 || kt < segs[0].nkt) {
            Ag = segs[0].A; Bg = segs[0].B; ldA = segs[0].ldA; ldB = segs[0].ldB;
        } else {
            Ag = segs[NS - 1].A; Bg = segs[NS - 1].B;
            ldA = segs[NS - 1].ldA; ldB = segs[NS - 1].ldB;
            kl = kt - segs[0].nkt;
        }
        const u16* As = Ag + (size_t)rowBase * ldA + kl * 64 + scol;
        const u16* Bs = Bg + (size_t)colBase * ldB + kl * 64 + scol;
        u16* dA = lds + buf * BUF;
        u16* dB = dA + AELE;
#pragma unroll
        for (int i = 0; i < PER; ++i) {
            int ci = wave * PER + i;     // chunk: 8 rows = 1024 B (64 lanes x 16 B)
            if (ci < 16) {
                gload_lds16(As + (size_t)(ci * 8 + sr) * ldA, dA + ci * 512);
            } else {
                int cb = ci - 16;
                gload_lds16(Bs + (size_t)(cb * 8 + sr) * ldB, dB + cb * 512);
            }
        }
    };

    stage(0, 0);
    int cur = 0;
    for (int kt = 0; kt < NT; ++kt) {
        if (kt + 1 < NT) {
            stage(kt + 1, cur ^ 1);                       // issue next-buffer loads
            asm volatile("s_waitcnt vmcnt(%0)" :: "i"(PER) : "memory");  // my cur loads done
        } else {
            asm volatile("s_waitcnt vmcnt(0)" ::: "memory");             // tail drain
        }
        __builtin_amdgcn_s_barrier();                     // all waves' cur loads done
        __builtin_amdgcn_sched_barrier(0);
        const u16* lA = lds + cur * BUF;
        const u16* lB = lA + AELE;
#pragma unroll
        for (int kk = 0; kk < 2; ++kk) {
            // T2 read: logical unit (kk*4 + lane>>4) XOR row&7 (= lane&7)
            const int ru = (((kk * 4 + (lane >> 4)) ^ (lane & 7)) * 8);
            bf16x8_t a[4], b[NACC];
#pragma unroll
            for (int m = 0; m < 4; ++m)
                a[m] = *(const bf16x8_t*)(lA + (wR + m * 16 + l15) * 64 + ru);
#pragma unroll
            for (int n = 0; n < NACC; ++n)
                b[n] = *(const bf16x8_t*)(lB + (wC + n * 16 + l15) * 64 + ru);
#pragma unroll
            for (int m = 0; m < 4; ++m)
#pragma unroll
                for (int n = 0; n < NACC; ++n)
                    acc[m][n] = __builtin_amdgcn_mfma_f32_16x16x32_bf16(a[m], b[n], acc[m][n], 0, 0, 0);
        }
        __builtin_amdgcn_s_barrier();                     // all reads of cur done
        __builtin_amdgcn_sched_barrier(0);                // pin next stage below barrier
        cur ^= 1;
    }
}

// block-id decode; optional bijective XCD swizzle (m204): contiguous wg chunks per XCD,
// col fastest -> col-blocks sharing an A-panel co-resident on one XCD's L2.
template<int NCOL, int NROW, int NWG, bool SWZ>
__device__ __forceinline__ void decode_wg(int o, int& col, int& row, int& kz) {
    int wg = o;
    if (SWZ) {
        constexpr int q = NWG / 8, r = NWG % 8;
        int xcd = o & 7, idx = o >> 3;
        wg = (xcd < r ? xcd * (q + 1) : r * (q + 1) + (xcd - r) * q) + idx;
    }
    col = wg % NCOL; int tmp = wg / NCOL; row = tmp % NROW; kz = tmp / NROW;
}

#define GEMM_PRE(BN, NCOL, NROW, NWG, SWZ)                                 \
    __shared__ u16 lds[2 * (128 * 64 + BN * 64)];                          \
    int col_, row_, kz_;                                                   \
    decode_wg<NCOL, NROW, NWG, SWZ>(blockIdx.x, col_, row_, kz_);          \
    int rowBase = row_ * 128, colBase = col_ * BN;                         \
    f32x4_t acc[4][BN / 32];                                               \
    _Pragma("unroll") for (int m = 0; m < 4; ++m)                          \
        _Pragma("unroll") for (int n = 0; n < BN / 32; ++n)                \
            acc[m][n] = (f32x4_t){0.f, 0.f, 0.f, 0.f};

#define EPI_IDX(BN)                                                        \
    const int lane = threadIdx.x & 63, wave = threadIdx.x >> 6;            \
    const int wR = (wave >> 1) * 64, wC = (wave & 1) * (BN / 2);           \
    const int l15 = lane & 15, r4 = (lane >> 4) * 4;

// z-GEMM: g = sigmoid(x@Wk + h0@Wr + bias) -> gbuf bf16 (4096 x 3072)
__global__ __launch_bounds__(256) void k_gemm1(const u16* xb, const u16* h0b,
                                               const u16* kT, const u16* rkT,
                                               const float* __restrict__ bias,
                                               u16* __restrict__ gbuf) {
    GEMM_PRE(64, 48, 32, 1536, false);
    Seg segs[2] = { { xb, kT, INF, INF, INF / 64 },
                    { h0b, rkT, UNITS_, UNITS_, UNITS_ / 64 } };
    gemm_core<2, 64>(segs, rowBase, colBase, lds, acc);
    EPI_IDX(64);
#pragma unroll
    for (int m = 0; m < 4; ++m)
#pragma unroll
        for (int n = 0; n < 2; ++n)
#pragma unroll
            for (int j = 0; j < 4; ++j) {
                int row = rowBase + wR + m * 16 + r4 + j;
                int col = colBase + wC + n * 16 + l15;
                gbuf[(size_t)row * 3072 + col] = f2bf(sigm(acc[m][n][j] + bias[col]));
            }
}

// agg GEMM: agg[k] = x@ski[k] + ss[k]@sks[k]  -> f32 (3 x 4096 x 512)
__global__ __launch_bounds__(256) void k_gemm2(const u16* xb, const u16* ssb,
                                               const u16* skiT, const u16* sksT,
                                               float* __restrict__ agg) {
    GEMM_PRE(64, 8, 32, 768, false);
    int k = kz_;
    Seg segs[2] = { { xb, skiT + (size_t)k * SUBD * INF, INF, INF, INF / 64 },
                    { ssb + (size_t)k * B_DIM * SUBD, sksT + (size_t)k * SUBD * SUBD, SUBD, SUBD, SUBD / 64 } };
    gemm_core<2, 64>(segs, rowBase, colBase, lds, acc);
    EPI_IDX(64);
#pragma unroll
    for (int m = 0; m < 4; ++m)
#pragma unroll
        for (int n = 0; n < 2; ++n)
#pragma unroll
            for (int j = 0; j < 4; ++j) {
                int row = rowBase + wR + m * 16 + r4 + j;
                int col = colBase + wC + n * 16 + l15;
                agg[((size_t)k * B_DIM + row) * SUBD + col] = acc[m][n][j];
            }
}

// sub_out GEMM: silu(agg)@bw^T + bases@ssw^T; epilogue -> new_sub_states (f32 out) + subflat bf16
__global__ __launch_bounds__(256) void k_gemm3(const u16* silu, const u16* bases,
                                               const u16* bwb, const u16* sswb,
                                               const float* __restrict__ srk,
                                               const float* __restrict__ ss,
                                               float* __restrict__ nss_out,
                                               u16* __restrict__ subfl) {
    GEMM_PRE(64, 8, 32, 768, true);   // XCD swizzle: col-blocks of a row-panel share one XCD L2
    int k = kz_;
    Seg segs[2] = { { silu + (size_t)k * B_DIM * SUBD, bwb + (size_t)k * SUBD * SUBD, SUBD, SUBD, SUBD / 64 },
                    { bases + (size_t)k * B_DIM * G3K, sswb + (size_t)k * SUBD * G3K, G3K, G3K, G3K / 64 } };
    gemm_core<2, 64>(segs, rowBase, colBase, lds, acc);
    EPI_IDX(64);
#pragma unroll
    for (int m = 0; m < 4; ++m)
#pragma unroll
        for (int n = 0; n < 2; ++n)
#pragma unroll
            for (int j = 0; j < 4; ++j) {
                int row = rowBase + wR + m * 16 + r4 + j;
                int col = colBase + wC + n * 16 + l15;
                float so = acc[m][n][j];
                float rh = srk[k * 1024 + col];
                float rx = srk[k * 1024 + 512 + col];
                size_t o = ((size_t)k * B_DIM + row) * SUBD + col;
                nss_out[o] = rh * so + rx * ss[o];
                subfl[(size_t)row * 1536 + k * SUBD + col] = f2bf(so);
            }
}

// output GEMM: h = sigmoid(subflat@aw + ab) * tanh(c_new)
__global__ __launch_bounds__(256) void k_gemm4(const u16* subfl, const u16* awT,
                                               const float* __restrict__ abias,
                                               const float* __restrict__ c_new,
                                               float* __restrict__ h_out) {
    GEMM_PRE(64, 16, 32, 512, false);
    Seg segs[1] = { { subfl, awT, 1536, 1536, 1536 / 64 } };
    gemm_core<1, 64>(segs, rowBase, colBase, lds, acc);
    EPI_IDX(64);
#pragma unroll
    for (int m = 0; m < 4; ++m)
#pragma unroll
        for (int n = 0; n < 2; ++n)
#pragma unroll
            for (int j = 0; j < 4; ++j) {
                int row = rowBase + wR + m * 16 + r4 + j;
                int col = colBase + wC + n * 16 + l15;
                float ov = sigm(acc[m][n][j] + abias[col]);
                h_out[(size_t)row * 1024 + col] = ov * tanh_(c_new[(size_t)row * 1024 + col]);
            }
}

// ---------------- launch ----------------
extern "C" void kernel_launch(void* const* d_in, const int* in_sizes, int n_in,
                              void* d_out, int out_size, void* d_ws, size_t ws_size,
                              hipStream_t stream) {
    const float* x    = (const float*)d_in[0];
    const float* h0   = (const float*)d_in[1];
    const float* c0   = (const float*)d_in[2];
    const float* ss   = (const float*)d_in[3];
    const float* Wk   = (const float*)d_in[4];
    const float* Wr   = (const float*)d_in[5];
    const float* bias = (const float*)d_in[6];
    const float* ski  = (const float*)d_in[7];
    const float* sks  = (const float*)d_in[8];
    const float* srk  = (const float*)d_in[9];
    const float* bw   = (const float*)d_in[10];
    const float* sw   = (const float*)d_in[11];
    const float* sc   = (const float*)d_in[12];
    const float* aw   = (const float*)d_in[13];
    const float* ab   = (const float*)d_in[14];

    float* out_h   = (float*)d_out;
    float* out_c   = out_h + (size_t)B_DIM * UNITS_;
    float* out_nss = out_c + (size_t)B_DIM * UNITS_;

    char* w = (char*)d_ws;
    auto take = [&](size_t bytes) -> char* {
        char* p = w; w += (bytes + 255) & ~(size_t)255; return p;
    };
    u16*   xb    = (u16*)take((size_t)B_DIM * INF * 2);
    u16*   h0b   = (u16*)take((size_t)B_DIM * UNITS_ * 2);
    u16*   ssb   = (u16*)take((size_t)NSUB_ * B_DIM * SUBD * 2);
    u16*   kT    = (u16*)take((size_t)3072 * INF * 2);
    u16*   rkT   = (u16*)take((size_t)3072 * UNITS_ * 2);
    u16*   skiT  = (u16*)take((size_t)NSUB_ * SUBD * INF * 2);
    u16*   sksT  = (u16*)take((size_t)NSUB_ * SUBD * SUBD * 2);
    u16*   bwb   = (u16*)take((size_t)NSUB_ * SUBD * SUBD * 2);
    u16*   sswb  = (u16*)take((size_t)NSUB_ * SUBD * G3K * 2);
    u16*   awT   = (u16*)take((size_t)UNITS_ * 1536 * 2);
    float* agg   = (float*)take((size_t)NSUB_ * B_DIM * SUBD * 4);
    u16*   siluB = (u16*)take((size_t)NSUB_ * B_DIM * SUBD * 2);
    u16*   subfl = (u16*)take((size_t)B_DIM * 1536 * 2);
    u16*   basesB= (u16*)take((size_t)NSUB_ * B_DIM * G3K * 2);
    u16*   gbuf  = basesB;   // alias: gbuf (25 MB) is dead before basesB is written

    dim3 tb(256);
    // converts
    k_f32_to_bf16<<<(B_DIM * INF / 4 + 255) / 256, tb, 0, stream>>>(x, xb, B_DIM * INF / 4);
    k_f32_to_bf16<<<(B_DIM * UNITS_ / 4 + 255) / 256, tb, 0, stream>>>(h0, h0b, B_DIM * UNITS_ / 4);
    k_f32_to_bf16<<<(NSUB_ * B_DIM * SUBD / 4 + 255) / 256, tb, 0, stream>>>(ss, ssb, NSUB_ * B_DIM * SUBD / 4);
    k_f32_to_bf16<<<(NSUB_ * SUBD * SUBD / 4 + 255) / 256, tb, 0, stream>>>(bw, bwb, NSUB_ * SUBD * SUBD / 4);
    k_ssw<<<(NSUB_ * SUBD * G3K / 4 + 255) / 256, tb, 0, stream>>>(sw, sc, sswb, NSUB_ * SUBD * G3K / 4);
    dim3 tt(32, 8);
    k_tconv<<<dim3(3072 / 32, INF / 32, 1), tt, 0, stream>>>(Wk, kT, INF, 3072, 0, 0);
    k_tconv<<<dim3(3072 / 32, UNITS_ / 32, 1), tt, 0, stream>>>(Wr, rkT, UNITS_, 3072, 0, 0);
    k_tconv<<<dim3(SUBD / 32, INF / 32, NSUB_), tt, 0, stream>>>(ski, skiT, INF, SUBD,
                                                                 (size_t)INF * SUBD, (size_t)SUBD * INF);
    k_tconv<<<dim3(SUBD / 32, SUBD / 32, NSUB_), tt, 0, stream>>>(sks, sksT, SUBD, SUBD,
                                                                  (size_t)SUBD * SUBD, (size_t)SUBD * SUBD);
    k_tconv<<<dim3(UNITS_ / 32, 1536 / 32, 1), tt, 0, stream>>>(aw, awT, 1536, UNITS_, 0, 0);

    // gate GEMM + c_new
    k_gemm1<<<1536, tb, 0, stream>>>(xb, h0b, kT, rkT, bias, gbuf);
    k_gemm2<<<768, tb, 0, stream>>>(xb, ssb, skiT, sksT, agg);
    k_cnew<<<(B_DIM * UNITS_ / 4 + 255) / 256, tb, 0, stream>>>(gbuf, c0, out_c, B_DIM * UNITS_ / 4);

    // spline bases + silu (gbuf region now dead -> basesB reuse OK)
    k_bases<<<4096, tb, 0, stream>>>(agg, basesB, siluB, NSUB_ * B_DIM * SUBD);

    // sub_out GEMM (base K=512 + spline K=4096), epilogue writes new_sub_states + subflat
    k_gemm3<<<768, tb, 0, stream>>>(siluB, basesB, bwb, sswb, srk, ss, out_nss, subfl);
    // aggregation GEMM + h_new
    k_gemm4<<<512, tb, 0, stream>>>(subfl, awT, ab, out_c, out_h);
}